// Round 1
// baseline (108.930 us; speedup 1.0000x reference)
//
#include <hip/hip_runtime.h>
#include <math.h>

#define T_DIM 12

// One thread processes TWO adjacent columns (a = .x/.y, b = .z/.w of a float4).
// Arrays are (T, N, 2) f32 -> row stride in float4 units is N/2.
__global__ __launch_bounds__(256) void ade_traj_kernel(
    const float4* __restrict__ inp,
    const float4* __restrict__ tgt,
    int npairs,          // N/2
    float* __restrict__ ws)   // ws[0] = sum(ade*sel), ws[1] = cnt
{
    const long stride = (long)gridDim.x * blockDim.x;
    float num = 0.0f;
    float cnt = 0.0f;

    for (long i = (long)blockIdx.x * blockDim.x + threadIdx.x; i < npairs; i += stride) {
        float ade_a = 0.0f, ade_b = 0.0f;
        float run_a = 0.0f, mx_a = 0.0f, sm_a = 0.0f;
        float run_b = 0.0f, mx_b = 0.0f, sm_b = 0.0f;
        // sliding window of previous two target points per column
        float p0ax = 0.f, p0ay = 0.f, p1ax = 0.f, p1ay = 0.f;
        float p0bx = 0.f, p0by = 0.f, p1bx = 0.f, p1by = 0.f;

        #pragma unroll
        for (int t = 0; t < T_DIM; ++t) {
            const long off = (long)t * npairs + i;
            float4 tv = tgt[off];
            float4 iv = inp[off];

            // ADE contribution
            {
                float dx = iv.x - tv.x, dy = iv.y - tv.y;
                ade_a += sqrtf(dx * dx + dy * dy);
                float dxb = iv.z - tv.z, dyb = iv.w - tv.w;
                ade_b += sqrtf(dxb * dxb + dyb * dyb);
            }

            if (t >= 2) {
                // Menger curvature for column a: points p0,p1,(tv.x,tv.y)
                {
                    float cx = tv.x, cy = tv.y;
                    float area = fabsf(p0ax * (p1ay - cy) + p1ax * (cy - p0ay) + cx * (p0ay - p1ay));
                    float ex01 = p1ax - p0ax, ey01 = p1ay - p0ay;
                    float ex12 = cx - p1ax,  ey12 = cy - p1ay;
                    float ex02 = cx - p0ax,  ey02 = cy - p0ay;
                    float dist = sqrtf(ex01 * ex01 + ey01 * ey01)
                               * sqrtf(ex12 * ex12 + ey12 * ey12)
                               * sqrtf(ex02 * ex02 + ey02 * ey02);
                    float k = 2.0f * area / dist;
                    if (__builtin_isnan(k)) k = 0.0f;   // jnp.where(isnan(k),0,k); inf kept
                    float m = (fabsf(k) >= 1.0f) ? 1.0f : 0.0f;
                    run_a += m;
                    mx_a = fmaxf(mx_a, run_a);
                    run_a *= m;
                    sm_a += m;
                }
                // column b
                {
                    float cx = tv.z, cy = tv.w;
                    float area = fabsf(p0bx * (p1by - cy) + p1bx * (cy - p0by) + cx * (p0by - p1by));
                    float ex01 = p1bx - p0bx, ey01 = p1by - p0by;
                    float ex12 = cx - p1bx,  ey12 = cy - p1by;
                    float ex02 = cx - p0bx,  ey02 = cy - p0by;
                    float dist = sqrtf(ex01 * ex01 + ey01 * ey01)
                               * sqrtf(ex12 * ex12 + ey12 * ey12)
                               * sqrtf(ex02 * ex02 + ey02 * ey02);
                    float k = 2.0f * area / dist;
                    if (__builtin_isnan(k)) k = 0.0f;
                    float m = (fabsf(k) >= 1.0f) ? 1.0f : 0.0f;
                    run_b += m;
                    mx_b = fmaxf(mx_b, run_b);
                    run_b *= m;
                    sm_b += m;
                }
            }
            // shift window
            p0ax = p1ax; p0ay = p1ay; p1ax = tv.x; p1ay = tv.y;
            p0bx = p1bx; p0by = p1by; p1bx = tv.z; p1by = tv.w;
        }

        // criteria = (mx >= 3) & (mx < 11) & (sum_mask > 0)
        bool sel_a = (mx_a >= 3.0f) && (mx_a < 11.0f) && (sm_a > 0.0f);
        bool sel_b = (mx_b >= 3.0f) && (mx_b < 11.0f) && (sm_b > 0.0f);
        if (sel_a) { num += ade_a * (1.0f / 12.0f); cnt += 1.0f; }
        if (sel_b) { num += ade_b * (1.0f / 12.0f); cnt += 1.0f; }
    }

    // wave(64) shuffle reduction
    #pragma unroll
    for (int off = 32; off > 0; off >>= 1) {
        num += __shfl_down(num, off, 64);
        cnt += __shfl_down(cnt, off, 64);
    }

    __shared__ float snum[4], scnt[4];
    const int wave = threadIdx.x >> 6;
    const int lane = threadIdx.x & 63;
    if (lane == 0) { snum[wave] = num; scnt[wave] = cnt; }
    __syncthreads();
    if (threadIdx.x == 0) {
        float n = 0.0f, c = 0.0f;
        #pragma unroll
        for (int w = 0; w < 4; ++w) { n += snum[w]; c += scnt[w]; }
        atomicAdd(&ws[0], n);
        atomicAdd(&ws[1], c);
    }
}

__global__ void ade_traj_finalize(const float* __restrict__ ws, float* __restrict__ out)
{
    if (threadIdx.x == 0 && blockIdx.x == 0) {
        float s = ws[0];
        float c = ws[1];
        out[0] = (c > 0.0f) ? (s / fmaxf(c, 1.0f)) : 0.0f;
    }
}

extern "C" void kernel_launch(void* const* d_in, const int* in_sizes, int n_in,
                              void* d_out, int out_size, void* d_ws, size_t ws_size,
                              hipStream_t stream) {
    const float* inp = (const float*)d_in[0];
    const float* tgt = (const float*)d_in[1];
    float* out = (float*)d_out;
    float* ws  = (float*)d_ws;

    // in_sizes[0] = T*N*2
    const int total = in_sizes[0];
    const int N = total / (T_DIM * 2);      // 1,500,000
    const int npairs = N / 2;               // 750,000 (N is even)

    // zero the two accumulators every launch (ws is poisoned once, never restored)
    hipMemsetAsync(ws, 0, 2 * sizeof(float), stream);

    const int block = 256;
    const int grid = (npairs + block - 1) / block;   // ~2930 blocks
    ade_traj_kernel<<<grid, block, 0, stream>>>(
        (const float4*)inp, (const float4*)tgt, npairs, ws);
    ade_traj_finalize<<<1, 64, 0, stream>>>(ws, out);
}